// Round 2
// baseline (342.870 us; speedup 1.0000x reference)
//
#include <hip/hip_runtime.h>
#include <hip/hip_bf16.h>

#define HH 128
#define EE 256
#define KK 4
#define RR 8
#define LL 2
#define BB 2
#define SS 1024
#define BT (BB*SS)      // 2048 tokens total
#define NJ (RR+2*HH)    // 264 dbc rows
#define GG 16           // scan chunks per sequence
#define CH (SS/GG)      // 64 timesteps per chunk
#define EPS 1e-5f
#define LOG2E 1.44269504088896f

__device__ __forceinline__ float silu_f(float v) {
    return v / (1.0f + __expf(-v));
}

// ---------------- K1: rmsnorm + in_proj (+bias) -> xz [2048][512] ------------
__global__ __launch_bounds__(512) void k_norm_inproj(
    const float* __restrict__ xres, const float* __restrict__ inw,
    const float* __restrict__ inb, const float* __restrict__ nw,
    float* __restrict__ xz)
{
    __shared__ float xn[16][128];
    const int bt0 = blockIdx.x * 16;
    const int tid = threadIdx.x;
    {   // phase A: rmsnorm for 16 tokens, 32 threads per token
        const int t = tid >> 5, g = tid & 31;
        const float4 xv = *(const float4*)(xres + (bt0 + t) * HH + g * 4);
        float ss = xv.x*xv.x + xv.y*xv.y + xv.z*xv.z + xv.w*xv.w;
        #pragma unroll
        for (int m = 16; m >= 1; m >>= 1) ss += __shfl_xor(ss, m);
        const float rs = rsqrtf(ss * (1.0f / HH) + EPS);
        const float4 wv = *(const float4*)(nw + g * 4);
        float4 o;
        o.x = xv.x * rs * wv.x; o.y = xv.y * rs * wv.y;
        o.z = xv.z * rs * wv.z; o.w = xv.w * rs * wv.w;
        *(float4*)(&xn[t][g * 4]) = o;
    }
    __syncthreads();
    // phase B: thread = output column j (512), 16-token accumulators
    const int j = tid;
    float acc[16];
    const float bj = inb[j];
    #pragma unroll
    for (int t = 0; t < 16; t++) acc[t] = bj;
    for (int k4 = 0; k4 < 32; k4++) {
        const int k = k4 * 4;
        const float w0 = inw[(k+0)*512 + j], w1 = inw[(k+1)*512 + j];
        const float w2 = inw[(k+2)*512 + j], w3 = inw[(k+3)*512 + j];
        #pragma unroll
        for (int t = 0; t < 16; t++) {
            const float4 xv = *(const float4*)(&xn[t][k]);
            acc[t] += w0*xv.x + w1*xv.y + w2*xv.z + w3*xv.w;
        }
    }
    #pragma unroll
    for (int t = 0; t < 16; t++) xz[(bt0 + t) * 512 + j] = acc[t];
}

// ---------------- K2A: causal conv + silu -> xcT [256][2048] -----------------
__global__ __launch_bounds__(256) void k_conv(
    const float* __restrict__ xz, const float* __restrict__ cw,
    const float* __restrict__ cb, float* __restrict__ xcT)
{
    const int e = threadIdx.x;
    const int tile = blockIdx.x;          // 128 tiles of 16 tokens
    const int b = tile >> 6;
    const int t0 = (tile & 63) * 16;
    const float w0 = cw[e*4+0], w1 = cw[e*4+1], w2 = cw[e*4+2], w3 = cw[e*4+3];
    const float bias = cb[e];
    const float* xp = xz + (size_t)(b * SS) * 512 + e;  // index token via *512
    float xm3 = (t0 >= 3) ? xp[(t0-3)*512] : 0.0f;
    float xm2 = (t0 >= 2) ? xp[(t0-2)*512] : 0.0f;
    float xm1 = (t0 >= 1) ? xp[(t0-1)*512] : 0.0f;
    float* orow = xcT + (size_t)e * BT + b * SS + t0;
    for (int jq = 0; jq < 4; jq++) {
        const int t = t0 + jq * 4;
        float4 ob; float v;
        const float x0 = xp[(t+0)*512];
        v = bias + w3*x0 + w2*xm1 + w1*xm2 + w0*xm3; ob.x = silu_f(v);
        const float x1 = xp[(t+1)*512];
        v = bias + w3*x1 + w2*x0 + w1*xm1 + w0*xm2;  ob.y = silu_f(v);
        const float x2 = xp[(t+2)*512];
        v = bias + w3*x2 + w2*x1 + w1*x0 + w0*xm1;   ob.z = silu_f(v);
        const float x3 = xp[(t+3)*512];
        v = bias + w3*x3 + w2*x2 + w1*x1 + w0*x0;    ob.w = silu_f(v);
        *(float4*)(orow + jq * 4) = ob;
        xm3 = x1; xm2 = x2; xm1 = x3;
    }
}

// ---------------- K2B: pl_proj -> dbcT [264][2048] ---------------------------
__global__ __launch_bounds__(320) void k_plproj(
    const float* __restrict__ xcT, const float* __restrict__ plw,
    const float* __restrict__ plb, float* __restrict__ dbcT)
{
    __shared__ float xs[8][256];
    const int bt0 = blockIdx.x * 8;
    const int tid = threadIdx.x;
    if (tid < 256) {
        const int e = tid;
        const float* p = xcT + (size_t)e * BT + bt0;
        const float4 a = *(const float4*)(p);
        const float4 c = *(const float4*)(p + 4);
        xs[0][e] = a.x; xs[1][e] = a.y; xs[2][e] = a.z; xs[3][e] = a.w;
        xs[4][e] = c.x; xs[5][e] = c.y; xs[6][e] = c.z; xs[7][e] = c.w;
    }
    __syncthreads();
    if (tid >= NJ) return;
    const int j = tid;
    float acc[8];
    const float bj = plb[j];
    #pragma unroll
    for (int t = 0; t < 8; t++) acc[t] = bj;
    for (int e4 = 0; e4 < 64; e4++) {
        const int e = e4 * 4;
        const float w0 = plw[(e+0)*NJ + j], w1 = plw[(e+1)*NJ + j];
        const float w2 = plw[(e+2)*NJ + j], w3 = plw[(e+3)*NJ + j];
        #pragma unroll
        for (int t = 0; t < 8; t++) {
            const float4 xv = *(const float4*)(&xs[t][e]);
            acc[t] += w0*xv.x + w1*xv.y + w2*xv.z + w3*xv.w;
        }
    }
    float* orow = dbcT + (size_t)j * BT + bt0;
    *(float4*)(orow)     = make_float4(acc[0], acc[1], acc[2], acc[3]);
    *(float4*)(orow + 4) = make_float4(acc[4], acc[5], acc[6], acc[7]);
}

// ---------------- K2C: delta = softplus(dt_proj), s = delta*xc ---------------
__global__ __launch_bounds__(256) void k_delta(
    const float* __restrict__ dbcT, const float* __restrict__ dtw,
    const float* __restrict__ dtb, const float* __restrict__ xcT,
    float* __restrict__ deltaT, float* __restrict__ sT)
{
    const int e = blockIdx.x >> 3;
    const int bt = (blockIdx.x & 7) * 256 + threadIdx.x;
    float d = dtb[e];
    #pragma unroll
    for (int r = 0; r < RR; r++) d += dtw[r*EE + e] * dbcT[(size_t)r * BT + bt];
    float sp;
    if (d > 15.0f) sp = d;
    else sp = log1pf(__expf(d));
    const float xc = xcT[(size_t)e * BT + bt];
    deltaT[(size_t)e * BT + bt] = sp;
    sT[(size_t)e * BT + bt] = sp * xc;
}

// ---------------- K3a: chunk-local scan -> y_local, h_end, dsum --------------
// grid = B*GG*EE blocks (e in low bits for B/C L2 reuse), block = 128 (n)
__global__ __launch_bounds__(128) void k_scan_local(
    const float* __restrict__ dbcT, const float* __restrict__ deltaT,
    const float* __restrict__ sT, const float* __restrict__ Alog,
    float* __restrict__ yT, float* __restrict__ hchain,
    float* __restrict__ dsum)
{
    __shared__ float part[16][132];
    __shared__ float ybuf[CH];
    const int blk = blockIdx.x;
    const int e = blk & 255;
    const int g = (blk >> 8) & 15;
    const int b = blk >> 12;
    const int n = threadIdx.x;
    const float An = -__expf(Alog[e * HH + n]) * LOG2E;
    const int t0 = g * CH;
    const float* Brow = dbcT + (size_t)(RR + n) * BT + b * SS + t0;
    const float* Crow = dbcT + (size_t)(RR + HH + n) * BT + b * SS + t0;
    const float* drow = deltaT + (size_t)e * BT + b * SS + t0;
    const float* srow = sT + (size_t)e * BT + b * SS + t0;
    float h = 0.0f, cum = 0.0f;
    const int tl = n >> 3, jj = n & 7;
    for (int sc = 0; sc < 4; sc++) {
        #pragma unroll
        for (int q = 0; q < 4; q++) {
            const int t = sc * 16 + q * 4;
            const float4 d4 = *(const float4*)(drow + t);
            const float4 s4 = *(const float4*)(srow + t);
            const float4 b4 = *(const float4*)(Brow + t);
            const float4 c4 = *(const float4*)(Crow + t);
            float a;
            cum += d4.x; a = exp2f(d4.x*An); h = a*h + s4.x*b4.x; part[q*4+0][n] = h*c4.x;
            cum += d4.y; a = exp2f(d4.y*An); h = a*h + s4.y*b4.y; part[q*4+1][n] = h*c4.y;
            cum += d4.z; a = exp2f(d4.z*An); h = a*h + s4.z*b4.z; part[q*4+2][n] = h*c4.z;
            cum += d4.w; a = exp2f(d4.w*An); h = a*h + s4.w*b4.w; part[q*4+3][n] = h*c4.w;
        }
        __syncthreads();
        float s0 = 0, s1 = 0, s2 = 0, s3 = 0;
        #pragma unroll
        for (int i = 0; i < 4; i++) {
            const float4 p = *(const float4*)(&part[tl][jj * 16 + i * 4]);
            s0 += p.x; s1 += p.y; s2 += p.z; s3 += p.w;
        }
        float r = (s0 + s1) + (s2 + s3);
        r += __shfl_xor(r, 1); r += __shfl_xor(r, 2); r += __shfl_xor(r, 4);
        if (jj == 0) ybuf[sc * 16 + tl] = r;
        __syncthreads();
    }
    if (n < CH) yT[(size_t)e * BT + b * SS + t0 + n] = ybuf[n];
    hchain[(size_t)(((b * EE + e) * GG) + g) * 128 + n] = h;
    if (n == 0) dsum[(b * EE + e) * GG + g] = cum;
}

// ---------------- K3b: chain chunk start-states (in-place over hchain) -------
// grid = B*EE blocks, block = 128. hchain in: h_end_local; out: h_start.
__global__ __launch_bounds__(128) void k_scan_combine(
    const float* __restrict__ Alog, const float* __restrict__ dsum,
    float* __restrict__ hchain)
{
    const int be = blockIdx.x;
    const int e = be & 255;
    const int n = threadIdx.x;
    const float An = -__expf(Alog[e * HH + n]) * LOG2E;
    float h = 0.0f;
    for (int g = 0; g < GG; g++) {
        float* p = hchain + (size_t)(be * GG + g) * 128 + n;
        const float he = *p;
        *p = h;                       // publish h_start for chunk g
        const float ds = dsum[be * GG + g];
        h = exp2f(An * ds) * h + he;
    }
}

// ---------------- K3c: cross-chunk correction: yT += C·(cumA ⊙ h_start) -----
// grid = B*15*EE blocks (g = 1..15), block = 128 (n)
__global__ __launch_bounds__(128) void k_scan_fix(
    const float* __restrict__ dbcT, const float* __restrict__ deltaT,
    const float* __restrict__ Alog, const float* __restrict__ hchain,
    float* __restrict__ yT)
{
    __shared__ float part[16][132];
    __shared__ float ybuf[CH];
    const int blk = blockIdx.x;
    const int e = blk & 255;
    const int r0 = blk >> 8;
    const int g = (r0 % 15) + 1;
    const int b = r0 / 15;
    const int n = threadIdx.x;
    const float An = -__expf(Alog[e * HH + n]) * LOG2E;
    const float w = hchain[(size_t)(((b * EE + e) * GG) + g) * 128 + n];
    const int t0 = g * CH;
    const float* Crow = dbcT + (size_t)(RR + HH + n) * BT + b * SS + t0;
    const float* drow = deltaT + (size_t)e * BT + b * SS + t0;
    float D = 0.0f;
    const int tl = n >> 3, jj = n & 7;
    for (int sc = 0; sc < 4; sc++) {
        #pragma unroll
        for (int q = 0; q < 4; q++) {
            const int t = sc * 16 + q * 4;
            const float4 d4 = *(const float4*)(drow + t);
            const float4 c4 = *(const float4*)(Crow + t);
            D += d4.x; part[q*4+0][n] = exp2f(An * D) * w * c4.x;
            D += d4.y; part[q*4+1][n] = exp2f(An * D) * w * c4.y;
            D += d4.z; part[q*4+2][n] = exp2f(An * D) * w * c4.z;
            D += d4.w; part[q*4+3][n] = exp2f(An * D) * w * c4.w;
        }
        __syncthreads();
        float s0 = 0, s1 = 0, s2 = 0, s3 = 0;
        #pragma unroll
        for (int i = 0; i < 4; i++) {
            const float4 p = *(const float4*)(&part[tl][jj * 16 + i * 4]);
            s0 += p.x; s1 += p.y; s2 += p.z; s3 += p.w;
        }
        float r = (s0 + s1) + (s2 + s3);
        r += __shfl_xor(r, 1); r += __shfl_xor(r, 2); r += __shfl_xor(r, 4);
        if (jj == 0) ybuf[sc * 16 + tl] = r;
        __syncthreads();
    }
    if (n < CH) yT[(size_t)e * BT + b * SS + t0 + n] += ybuf[n];
}

// ---------------- K4: gate + out_proj + residual (in-place xres) -------------
__global__ __launch_bounds__(256) void k_gate_outproj(
    const float* __restrict__ yT, const float* __restrict__ xcT,
    const float* __restrict__ xz, const float* __restrict__ Dp,
    const float* __restrict__ ow, const float* __restrict__ ob,
    float* __restrict__ xres)
{
    __shared__ float gs[16][256];
    __shared__ float part2[16][128];
    const int bt0 = blockIdx.x * 16;
    const int tid = threadIdx.x;
    {   // phase A: g = (y + Dp*xc) * silu(skip)
        const int e = tid;
        const float dp = Dp[e];
        const float* yp = yT + (size_t)e * BT + bt0;
        const float* xp = xcT + (size_t)e * BT + bt0;
        #pragma unroll
        for (int tq = 0; tq < 4; tq++) {
            const float4 y4 = *(const float4*)(yp + tq * 4);
            const float4 x4 = *(const float4*)(xp + tq * 4);
            float sk;
            sk = xz[(size_t)(bt0 + tq*4 + 0) * 512 + 256 + e];
            gs[tq*4+0][e] = (y4.x + dp * x4.x) * silu_f(sk);
            sk = xz[(size_t)(bt0 + tq*4 + 1) * 512 + 256 + e];
            gs[tq*4+1][e] = (y4.y + dp * x4.y) * silu_f(sk);
            sk = xz[(size_t)(bt0 + tq*4 + 2) * 512 + 256 + e];
            gs[tq*4+2][e] = (y4.z + dp * x4.z) * silu_f(sk);
            sk = xz[(size_t)(bt0 + tq*4 + 3) * 512 + 256 + e];
            gs[tq*4+3][e] = (y4.w + dp * x4.w) * silu_f(sk);
        }
    }
    __syncthreads();
    // phase B: split-K GEMM, thread = (j, kh)
    const int j = tid & 127;
    const int kh = tid >> 7;
    float acc[16];
    #pragma unroll
    for (int t = 0; t < 16; t++) acc[t] = 0.0f;
    for (int e4 = 0; e4 < 32; e4++) {
        const int e = kh * 128 + e4 * 4;
        const float w0 = ow[(e+0)*HH + j], w1 = ow[(e+1)*HH + j];
        const float w2 = ow[(e+2)*HH + j], w3 = ow[(e+3)*HH + j];
        #pragma unroll
        for (int t = 0; t < 16; t++) {
            const float4 g4 = *(const float4*)(&gs[t][e]);
            acc[t] += w0*g4.x + w1*g4.y + w2*g4.z + w3*g4.w;
        }
    }
    if (kh == 1) {
        #pragma unroll
        for (int t = 0; t < 16; t++) part2[t][j] = acc[t];
    }
    __syncthreads();
    if (kh == 0) {
        const float bj = ob[j];
        #pragma unroll
        for (int t = 0; t < 16; t++) {
            const float r = acc[t] + part2[t][j] + bj
                          + xres[(size_t)(bt0 + t) * HH + j];
            xres[(size_t)(bt0 + t) * HH + j] = r;
        }
    }
}

// ---------------- K5: final rmsnorm -> d_out ---------------------------------
__global__ __launch_bounds__(64) void k_finalnorm(
    const float* __restrict__ xres, const float* __restrict__ fw,
    float* __restrict__ out)
{
    const int bt = blockIdx.x;
    const int tid = threadIdx.x;
    const float2 v = *(const float2*)(xres + (size_t)bt * HH + tid * 2);
    float ss = v.x*v.x + v.y*v.y;
    #pragma unroll
    for (int m = 32; m >= 1; m >>= 1) ss += __shfl_xor(ss, m);
    const float rs = rsqrtf(ss * (1.0f / HH) + EPS);
    const float2 w = *(const float2*)(fw + tid * 2);
    float2 o; o.x = v.x * rs * w.x; o.y = v.y * rs * w.y;
    *(float2*)(out + (size_t)bt * HH + tid * 2) = o;
}

extern "C" void kernel_launch(void* const* d_in, const int* in_sizes, int n_in,
                              void* d_out, int out_size, void* d_ws, size_t ws_size,
                              hipStream_t stream)
{
    const float* x      = (const float*)d_in[0];
    const float* in_w   = (const float*)d_in[1];
    const float* in_b   = (const float*)d_in[2];
    const float* out_w  = (const float*)d_in[3];
    const float* out_b  = (const float*)d_in[4];
    const float* pl_w   = (const float*)d_in[5];
    const float* pl_b   = (const float*)d_in[6];
    const float* dt_w   = (const float*)d_in[7];
    const float* dt_b   = (const float*)d_in[8];
    const float* conv_w = (const float*)d_in[9];
    const float* conv_b = (const float*)d_in[10];
    const float* A_log  = (const float*)d_in[11];
    const float* Dp     = (const float*)d_in[12];
    const float* norm_w = (const float*)d_in[13];
    const float* fnw    = (const float*)d_in[14];

    float* ws     = (float*)d_ws;
    float* xres   = ws;                        // 262144
    float* xz     = xres   + 262144;           // 1048576
    float* xcT    = xz     + 1048576;          // 524288
    float* dbcT   = xcT    + 524288;           // 540672
    float* deltaT = dbcT   + 540672;           // 524288
    float* sT     = deltaT + 524288;           // 524288
    float* yT     = sT     + 524288;           // 524288
    float* hchain = yT     + 524288;           // B*E*GG*128 = 1048576
    float* dsum   = hchain + 1048576;          // B*E*GG = 8192  (total ~20 MB)

    hipMemcpyAsync(xres, x, (size_t)262144 * sizeof(float),
                   hipMemcpyDeviceToDevice, stream);

    for (int l = 0; l < LL; l++) {
        k_norm_inproj<<<BT/16, 512, 0, stream>>>(
            xres, in_w + (size_t)l*HH*2*EE, in_b + (size_t)l*2*EE,
            norm_w + (size_t)l*HH, xz);
        k_conv<<<128, 256, 0, stream>>>(
            xz, conv_w + (size_t)l*EE*KK, conv_b + (size_t)l*EE, xcT);
        k_plproj<<<BT/8, 320, 0, stream>>>(
            xcT, pl_w + (size_t)l*EE*NJ, pl_b + (size_t)l*NJ, dbcT);
        k_delta<<<EE*8, 256, 0, stream>>>(
            dbcT, dt_w + (size_t)l*RR*EE, dt_b + (size_t)l*EE, xcT, deltaT, sT);
        k_scan_local<<<BB*GG*EE, 128, 0, stream>>>(
            dbcT, deltaT, sT, A_log + (size_t)l*EE*HH, yT, hchain, dsum);
        k_scan_combine<<<BB*EE, 128, 0, stream>>>(
            A_log + (size_t)l*EE*HH, dsum, hchain);
        k_scan_fix<<<BB*(GG-1)*EE, 128, 0, stream>>>(
            dbcT, deltaT, A_log + (size_t)l*EE*HH, hchain, yT);
        k_gate_outproj<<<BT/16, 256, 0, stream>>>(
            yT, xcT, xz, Dp + (size_t)l*EE,
            out_w + (size_t)l*EE*HH, out_b + (size_t)l*HH, xres);
    }
    k_finalnorm<<<BT, 64, 0, stream>>>(xres, fnw, (float*)d_out);
}

// Round 3
// 283.585 us; speedup vs baseline: 1.2091x; 1.2091x over previous
//
#include <hip/hip_runtime.h>
#include <hip/hip_bf16.h>

#define HH 128
#define EE 256
#define KK 4
#define RR 8
#define LL 2
#define BB 2
#define SS 1024
#define BT (BB*SS)      // 2048 tokens total
#define NJ (RR+2*HH)    // 264 dbc rows
#define GG 16           // scan chunks per sequence
#define CH (SS/GG)      // 64 timesteps per chunk
#define EPS 1e-5f
#define LOG2E 1.44269504088896f

__device__ __forceinline__ float silu_f(float v) {
    return v / (1.0f + __expf(-v));
}

// ---------------- K1: rmsnorm + in_proj (+bias) -> xz [2048][512] ------------
__global__ __launch_bounds__(512) void k_norm_inproj(
    const float* __restrict__ xres, const float* __restrict__ inw,
    const float* __restrict__ inb, const float* __restrict__ nw,
    float* __restrict__ xz)
{
    __shared__ float xn[16][128];
    const int bt0 = blockIdx.x * 16;
    const int tid = threadIdx.x;
    {   // phase A: rmsnorm for 16 tokens, 32 threads per token
        const int t = tid >> 5, g = tid & 31;
        const float4 xv = *(const float4*)(xres + (bt0 + t) * HH + g * 4);
        float ss = xv.x*xv.x + xv.y*xv.y + xv.z*xv.z + xv.w*xv.w;
        #pragma unroll
        for (int m = 16; m >= 1; m >>= 1) ss += __shfl_xor(ss, m);
        const float rs = rsqrtf(ss * (1.0f / HH) + EPS);
        const float4 wv = *(const float4*)(nw + g * 4);
        float4 o;
        o.x = xv.x * rs * wv.x; o.y = xv.y * rs * wv.y;
        o.z = xv.z * rs * wv.z; o.w = xv.w * rs * wv.w;
        *(float4*)(&xn[t][g * 4]) = o;
    }
    __syncthreads();
    // phase B: thread = output column j (512), 16-token accumulators
    const int j = tid;
    float acc[16];
    const float bj = inb[j];
    #pragma unroll
    for (int t = 0; t < 16; t++) acc[t] = bj;
    float w0n = inw[0*512 + j], w1n = inw[1*512 + j];
    float w2n = inw[2*512 + j], w3n = inw[3*512 + j];
    for (int k4 = 0; k4 < 32; k4++) {
        const float w0 = w0n, w1 = w1n, w2 = w2n, w3 = w3n;
        if (k4 < 31) {
            const int k = (k4 + 1) * 4;
            w0n = inw[(k+0)*512 + j]; w1n = inw[(k+1)*512 + j];
            w2n = inw[(k+2)*512 + j]; w3n = inw[(k+3)*512 + j];
        }
        const int k = k4 * 4;
        #pragma unroll
        for (int t = 0; t < 16; t++) {
            const float4 xv = *(const float4*)(&xn[t][k]);
            acc[t] += w0*xv.x + w1*xv.y + w2*xv.z + w3*xv.w;
        }
    }
    #pragma unroll
    for (int t = 0; t < 16; t++) xz[(bt0 + t) * 512 + j] = acc[t];
}

// ---------------- K2A: causal conv + silu -> xcT [256][2048] -----------------
__global__ __launch_bounds__(256) void k_conv(
    const float* __restrict__ xz, const float* __restrict__ cw,
    const float* __restrict__ cb, float* __restrict__ xcT)
{
    const int e = threadIdx.x;
    const int tile = blockIdx.x;          // 128 tiles of 16 tokens
    const int b = tile >> 6;
    const int t0 = (tile & 63) * 16;
    const float w0 = cw[e*4+0], w1 = cw[e*4+1], w2 = cw[e*4+2], w3 = cw[e*4+3];
    const float bias = cb[e];
    const float* xp = xz + (size_t)(b * SS) * 512 + e;  // index token via *512
    float xm3 = (t0 >= 3) ? xp[(t0-3)*512] : 0.0f;
    float xm2 = (t0 >= 2) ? xp[(t0-2)*512] : 0.0f;
    float xm1 = (t0 >= 1) ? xp[(t0-1)*512] : 0.0f;
    float* orow = xcT + (size_t)e * BT + b * SS + t0;
    for (int jq = 0; jq < 4; jq++) {
        const int t = t0 + jq * 4;
        float4 ob; float v;
        const float x0 = xp[(t+0)*512];
        v = bias + w3*x0 + w2*xm1 + w1*xm2 + w0*xm3; ob.x = silu_f(v);
        const float x1 = xp[(t+1)*512];
        v = bias + w3*x1 + w2*x0 + w1*xm1 + w0*xm2;  ob.y = silu_f(v);
        const float x2 = xp[(t+2)*512];
        v = bias + w3*x2 + w2*x1 + w1*x0 + w0*xm1;   ob.z = silu_f(v);
        const float x3 = xp[(t+3)*512];
        v = bias + w3*x3 + w2*x2 + w1*x1 + w0*x0;    ob.w = silu_f(v);
        *(float4*)(orow + jq * 4) = ob;
        xm3 = x1; xm2 = x2; xm1 = x3;
    }
}

// ---------------- K2B: pl_proj -> dbcT [264][2048] ---------------------------
__global__ __launch_bounds__(320) void k_plproj(
    const float* __restrict__ xcT, const float* __restrict__ plw,
    const float* __restrict__ plb, float* __restrict__ dbcT)
{
    __shared__ float xs[8][256];
    const int bt0 = blockIdx.x * 8;
    const int tid = threadIdx.x;
    if (tid < 256) {
        const int e = tid;
        const float* p = xcT + (size_t)e * BT + bt0;
        const float4 a = *(const float4*)(p);
        const float4 c = *(const float4*)(p + 4);
        xs[0][e] = a.x; xs[1][e] = a.y; xs[2][e] = a.z; xs[3][e] = a.w;
        xs[4][e] = c.x; xs[5][e] = c.y; xs[6][e] = c.z; xs[7][e] = c.w;
    }
    __syncthreads();
    if (tid >= NJ) return;
    const int j = tid;
    float acc[8];
    const float bj = plb[j];
    #pragma unroll
    for (int t = 0; t < 8; t++) acc[t] = bj;
    float w0n = plw[0*NJ + j], w1n = plw[1*NJ + j];
    float w2n = plw[2*NJ + j], w3n = plw[3*NJ + j];
    for (int e4 = 0; e4 < 64; e4++) {
        const float w0 = w0n, w1 = w1n, w2 = w2n, w3 = w3n;
        if (e4 < 63) {
            const int e = (e4 + 1) * 4;
            w0n = plw[(e+0)*NJ + j]; w1n = plw[(e+1)*NJ + j];
            w2n = plw[(e+2)*NJ + j]; w3n = plw[(e+3)*NJ + j];
        }
        const int e = e4 * 4;
        #pragma unroll
        for (int t = 0; t < 8; t++) {
            const float4 xv = *(const float4*)(&xs[t][e]);
            acc[t] += w0*xv.x + w1*xv.y + w2*xv.z + w3*xv.w;
        }
    }
    float* orow = dbcT + (size_t)j * BT + bt0;
    *(float4*)(orow)     = make_float4(acc[0], acc[1], acc[2], acc[3]);
    *(float4*)(orow + 4) = make_float4(acc[4], acc[5], acc[6], acc[7]);
}

// ---------------- K2C: delta = softplus(dt_proj), s = delta*xc ---------------
__global__ __launch_bounds__(256) void k_delta(
    const float* __restrict__ dbcT, const float* __restrict__ dtw,
    const float* __restrict__ dtb, const float* __restrict__ xcT,
    float* __restrict__ deltaT, float* __restrict__ sT)
{
    const int e = blockIdx.x >> 3;
    const int bt = (blockIdx.x & 7) * 256 + threadIdx.x;
    float d = dtb[e];
    #pragma unroll
    for (int r = 0; r < RR; r++) d += dtw[r*EE + e] * dbcT[(size_t)r * BT + bt];
    float sp;
    if (d > 15.0f) sp = d;
    else sp = log1pf(__expf(d));
    const float xc = xcT[(size_t)e * BT + bt];
    deltaT[(size_t)e * BT + bt] = sp;
    sT[(size_t)e * BT + bt] = sp * xc;
}

// ---------------- K3a: chunk-local scan, 4 e's per block ---------------------
// grid = B*GG*(EE/4) = 2048, block = 128 (n). XCD-swizzled so all 64 blocks
// of one (b,g) land on the same XCD (B/C rows then hit local L2).
__global__ __launch_bounds__(128, 3) void k_scan_local(
    const float* __restrict__ dbcT, const float* __restrict__ deltaT,
    const float* __restrict__ sT, const float* __restrict__ Alog,
    float* __restrict__ yT, float* __restrict__ hchain,
    float* __restrict__ dsum)
{
    __shared__ float part[4][16][68];
    __shared__ float ybuf[4][CH];
    const int blk = blockIdx.x;
    const int wgid = (blk & 7) * 256 + (blk >> 3);   // bijective, 8 XCD chunks
    const int eq = wgid & 63;
    const int r0 = wgid >> 6;       // 0..31 = (b,g)
    const int b = r0 >> 4;
    const int g = r0 & 15;
    const int e0 = eq * 4;
    const int n = threadIdx.x;
    const int t0 = g * CH;

    float An[4], h[4], cum[4];
    #pragma unroll
    for (int ee = 0; ee < 4; ee++) {
        An[ee] = -__expf(Alog[(e0 + ee) * HH + n]) * LOG2E;
        h[ee] = 0.0f; cum[ee] = 0.0f;
    }
    const float* Brow = dbcT + (size_t)(RR + n) * BT + b * SS + t0;
    const float* Crow = dbcT + (size_t)(RR + HH + n) * BT + b * SS + t0;
    const float* dr[4]; const float* sr[4];
    #pragma unroll
    for (int ee = 0; ee < 4; ee++) {
        dr[ee] = deltaT + (size_t)(e0 + ee) * BT + b * SS + t0;
        sr[ee] = sT + (size_t)(e0 + ee) * BT + b * SS + t0;
    }
    // prefetch t-quad 0
    float4 pB = *(const float4*)Brow;
    float4 pC = *(const float4*)Crow;
    float4 pd[4], ps[4];
    #pragma unroll
    for (int ee = 0; ee < 4; ee++) {
        pd[ee] = *(const float4*)dr[ee];
        ps[ee] = *(const float4*)sr[ee];
    }
    const int tl = n >> 3, jj = n & 7;
    for (int sc = 0; sc < 4; sc++) {
        #pragma unroll
        for (int q = 0; q < 4; q++) {
            const int qq = sc * 4 + q;
            const float4 cB = pB, cC = pC;
            float4 cd[4], cs[4];
            #pragma unroll
            for (int ee = 0; ee < 4; ee++) { cd[ee] = pd[ee]; cs[ee] = ps[ee]; }
            if (qq < 15) {
                const int t = (qq + 1) * 4;
                pB = *(const float4*)(Brow + t);
                pC = *(const float4*)(Crow + t);
                #pragma unroll
                for (int ee = 0; ee < 4; ee++) {
                    pd[ee] = *(const float4*)(dr[ee] + t);
                    ps[ee] = *(const float4*)(sr[ee] + t);
                }
            }
            #pragma unroll
            for (int ee = 0; ee < 4; ee++) {
                float a;
                a = exp2f(cd[ee].x * An[ee]); h[ee] = a*h[ee] + cs[ee].x*cB.x;
                part[ee][q*4+0][n] = h[ee] * cC.x;
                a = exp2f(cd[ee].y * An[ee]); h[ee] = a*h[ee] + cs[ee].y*cB.y;
                part[ee][q*4+1][n] = h[ee] * cC.y;
                a = exp2f(cd[ee].z * An[ee]); h[ee] = a*h[ee] + cs[ee].z*cB.z;
                part[ee][q*4+2][n] = h[ee] * cC.z;
                a = exp2f(cd[ee].w * An[ee]); h[ee] = a*h[ee] + cs[ee].w*cB.w;
                part[ee][q*4+3][n] = h[ee] * cC.w;
                cum[ee] += (cd[ee].x + cd[ee].y) + (cd[ee].z + cd[ee].w);
            }
        }
        __syncthreads();
        #pragma unroll
        for (int ee = 0; ee < 4; ee++) {
            float s0 = 0, s1 = 0, s2 = 0, s3 = 0;
            #pragma unroll
            for (int i = 0; i < 4; i++) {
                const float4 p = *(const float4*)(&part[ee][tl][jj*16 + i*4]);
                s0 += p.x; s1 += p.y; s2 += p.z; s3 += p.w;
            }
            float r = (s0 + s1) + (s2 + s3);
            r += __shfl_xor(r, 1); r += __shfl_xor(r, 2); r += __shfl_xor(r, 4);
            if (jj == 0) ybuf[ee][sc*16 + tl] = r;
        }
        __syncthreads();
    }
    // epilogue
    {
        const int ee = n >> 5, tt = n & 31;
        float* yp = yT + (size_t)(e0 + ee) * BT + b * SS + t0;
        yp[tt] = ybuf[ee][tt];
        yp[tt + 32] = ybuf[ee][tt + 32];
    }
    #pragma unroll
    for (int ee = 0; ee < 4; ee++)
        hchain[(size_t)(((b * EE + e0 + ee) * GG) + g) * 128 + n] = h[ee];
    if (n == 0) {
        #pragma unroll
        for (int ee = 0; ee < 4; ee++)
            dsum[(b * EE + e0 + ee) * GG + g] = cum[ee];
    }
}

// ---------------- K3b: chain chunk start-states (in-place over hchain) -------
__global__ __launch_bounds__(128) void k_scan_combine(
    const float* __restrict__ Alog, const float* __restrict__ dsum,
    float* __restrict__ hchain)
{
    const int be = blockIdx.x;
    const int e = be & 255;
    const int n = threadIdx.x;
    const float An = -__expf(Alog[e * HH + n]) * LOG2E;
    float h = 0.0f;
    for (int g = 0; g < GG; g++) {
        float* p = hchain + (size_t)(be * GG + g) * 128 + n;
        const float he = *p;
        *p = h;                       // publish h_start for chunk g
        const float ds = dsum[be * GG + g];
        h = exp2f(An * ds) * h + he;
    }
}

// ---------------- K3c: cross-chunk correction, 4 e's per block ---------------
// grid = B*15*(EE/4) = 1920, block = 128 (n). Same XCD swizzle idea.
__global__ __launch_bounds__(128, 3) void k_scan_fix(
    const float* __restrict__ dbcT, const float* __restrict__ deltaT,
    const float* __restrict__ Alog, const float* __restrict__ hchain,
    float* __restrict__ yT)
{
    __shared__ float part[4][16][68];
    __shared__ float ybuf[4][CH];
    const int blk = blockIdx.x;
    const int wgid = (blk & 7) * 240 + (blk >> 3);
    const int eq = wgid & 63;
    const int r0 = wgid >> 6;       // 0..29
    const int b = r0 / 15;
    const int g = 1 + (r0 % 15);
    const int e0 = eq * 4;
    const int n = threadIdx.x;
    const int t0 = g * CH;

    float An[4], w[4], D[4];
    #pragma unroll
    for (int ee = 0; ee < 4; ee++) {
        An[ee] = -__expf(Alog[(e0 + ee) * HH + n]) * LOG2E;
        w[ee] = hchain[(size_t)(((b * EE + e0 + ee) * GG) + g) * 128 + n];
        D[ee] = 0.0f;
    }
    const float* Crow = dbcT + (size_t)(RR + HH + n) * BT + b * SS + t0;
    const float* dr[4];
    #pragma unroll
    for (int ee = 0; ee < 4; ee++)
        dr[ee] = deltaT + (size_t)(e0 + ee) * BT + b * SS + t0;

    float4 pC = *(const float4*)Crow;
    float4 pd[4];
    #pragma unroll
    for (int ee = 0; ee < 4; ee++) pd[ee] = *(const float4*)dr[ee];

    const int tl = n >> 3, jj = n & 7;
    for (int sc = 0; sc < 4; sc++) {
        #pragma unroll
        for (int q = 0; q < 4; q++) {
            const int qq = sc * 4 + q;
            const float4 cC = pC;
            float4 cd[4];
            #pragma unroll
            for (int ee = 0; ee < 4; ee++) cd[ee] = pd[ee];
            if (qq < 15) {
                const int t = (qq + 1) * 4;
                pC = *(const float4*)(Crow + t);
                #pragma unroll
                for (int ee = 0; ee < 4; ee++)
                    pd[ee] = *(const float4*)(dr[ee] + t);
            }
            #pragma unroll
            for (int ee = 0; ee < 4; ee++) {
                D[ee] += cd[ee].x; part[ee][q*4+0][n] = exp2f(An[ee]*D[ee]) * w[ee] * cC.x;
                D[ee] += cd[ee].y; part[ee][q*4+1][n] = exp2f(An[ee]*D[ee]) * w[ee] * cC.y;
                D[ee] += cd[ee].z; part[ee][q*4+2][n] = exp2f(An[ee]*D[ee]) * w[ee] * cC.z;
                D[ee] += cd[ee].w; part[ee][q*4+3][n] = exp2f(An[ee]*D[ee]) * w[ee] * cC.w;
            }
        }
        __syncthreads();
        #pragma unroll
        for (int ee = 0; ee < 4; ee++) {
            float s0 = 0, s1 = 0, s2 = 0, s3 = 0;
            #pragma unroll
            for (int i = 0; i < 4; i++) {
                const float4 p = *(const float4*)(&part[ee][tl][jj*16 + i*4]);
                s0 += p.x; s1 += p.y; s2 += p.z; s3 += p.w;
            }
            float r = (s0 + s1) + (s2 + s3);
            r += __shfl_xor(r, 1); r += __shfl_xor(r, 2); r += __shfl_xor(r, 4);
            if (jj == 0) ybuf[ee][sc*16 + tl] = r;
        }
        __syncthreads();
    }
    {
        const int ee = n >> 5, tt = n & 31;
        float* yp = yT + (size_t)(e0 + ee) * BT + b * SS + t0;
        yp[tt] += ybuf[ee][tt];
        yp[tt + 32] += ybuf[ee][tt + 32];
    }
}

// ---------------- K4: gate + out_proj + residual (in-place xres) -------------
__global__ __launch_bounds__(256) void k_gate_outproj(
    const float* __restrict__ yT, const float* __restrict__ xcT,
    const float* __restrict__ xz, const float* __restrict__ Dp,
    const float* __restrict__ ow, const float* __restrict__ ob,
    float* __restrict__ xres)
{
    __shared__ float gs[16][256];
    __shared__ float part2[16][128];
    const int bt0 = blockIdx.x * 16;
    const int tid = threadIdx.x;
    {   // phase A: g = (y + Dp*xc) * silu(skip)
        const int e = tid;
        const float dp = Dp[e];
        const float* yp = yT + (size_t)e * BT + bt0;
        const float* xp = xcT + (size_t)e * BT + bt0;
        #pragma unroll
        for (int tq = 0; tq < 4; tq++) {
            const float4 y4 = *(const float4*)(yp + tq * 4);
            const float4 x4 = *(const float4*)(xp + tq * 4);
            float sk;
            sk = xz[(size_t)(bt0 + tq*4 + 0) * 512 + 256 + e];
            gs[tq*4+0][e] = (y4.x + dp * x4.x) * silu_f(sk);
            sk = xz[(size_t)(bt0 + tq*4 + 1) * 512 + 256 + e];
            gs[tq*4+1][e] = (y4.y + dp * x4.y) * silu_f(sk);
            sk = xz[(size_t)(bt0 + tq*4 + 2) * 512 + 256 + e];
            gs[tq*4+2][e] = (y4.z + dp * x4.z) * silu_f(sk);
            sk = xz[(size_t)(bt0 + tq*4 + 3) * 512 + 256 + e];
            gs[tq*4+3][e] = (y4.w + dp * x4.w) * silu_f(sk);
        }
    }
    __syncthreads();
    // phase B: split-K GEMM, thread = (j, kh)
    const int j = tid & 127;
    const int kh = tid >> 7;
    float acc[16];
    #pragma unroll
    for (int t = 0; t < 16; t++) acc[t] = 0.0f;
    const int eb = kh * 128;
    float w0n = ow[(eb+0)*HH + j], w1n = ow[(eb+1)*HH + j];
    float w2n = ow[(eb+2)*HH + j], w3n = ow[(eb+3)*HH + j];
    for (int e4 = 0; e4 < 32; e4++) {
        const float w0 = w0n, w1 = w1n, w2 = w2n, w3 = w3n;
        if (e4 < 31) {
            const int e = eb + (e4 + 1) * 4;
            w0n = ow[(e+0)*HH + j]; w1n = ow[(e+1)*HH + j];
            w2n = ow[(e+2)*HH + j]; w3n = ow[(e+3)*HH + j];
        }
        const int e = eb + e4 * 4;
        #pragma unroll
        for (int t = 0; t < 16; t++) {
            const float4 g4 = *(const float4*)(&gs[t][e]);
            acc[t] += w0*g4.x + w1*g4.y + w2*g4.z + w3*g4.w;
        }
    }
    if (kh == 1) {
        #pragma unroll
        for (int t = 0; t < 16; t++) part2[t][j] = acc[t];
    }
    __syncthreads();
    if (kh == 0) {
        const float bj = ob[j];
        #pragma unroll
        for (int t = 0; t < 16; t++) {
            const float r = acc[t] + part2[t][j] + bj
                          + xres[(size_t)(bt0 + t) * HH + j];
            xres[(size_t)(bt0 + t) * HH + j] = r;
        }
    }
}

// ---------------- K5: final rmsnorm -> d_out ---------------------------------
__global__ __launch_bounds__(64) void k_finalnorm(
    const float* __restrict__ xres, const float* __restrict__ fw,
    float* __restrict__ out)
{
    const int bt = blockIdx.x;
    const int tid = threadIdx.x;
    const float2 v = *(const float2*)(xres + (size_t)bt * HH + tid * 2);
    float ss = v.x*v.x + v.y*v.y;
    #pragma unroll
    for (int m = 32; m >= 1; m >>= 1) ss += __shfl_xor(ss, m);
    const float rs = rsqrtf(ss * (1.0f / HH) + EPS);
    const float2 w = *(const float2*)(fw + tid * 2);
    float2 o; o.x = v.x * rs * w.x; o.y = v.y * rs * w.y;
    *(float2*)(out + (size_t)bt * HH + tid * 2) = o;
}

extern "C" void kernel_launch(void* const* d_in, const int* in_sizes, int n_in,
                              void* d_out, int out_size, void* d_ws, size_t ws_size,
                              hipStream_t stream)
{
    const float* x      = (const float*)d_in[0];
    const float* in_w   = (const float*)d_in[1];
    const float* in_b   = (const float*)d_in[2];
    const float* out_w  = (const float*)d_in[3];
    const float* out_b  = (const float*)d_in[4];
    const float* pl_w   = (const float*)d_in[5];
    const float* pl_b   = (const float*)d_in[6];
    const float* dt_w   = (const float*)d_in[7];
    const float* dt_b   = (const float*)d_in[8];
    const float* conv_w = (const float*)d_in[9];
    const float* conv_b = (const float*)d_in[10];
    const float* A_log  = (const float*)d_in[11];
    const float* Dp     = (const float*)d_in[12];
    const float* norm_w = (const float*)d_in[13];
    const float* fnw    = (const float*)d_in[14];

    float* ws     = (float*)d_ws;
    float* xres   = ws;                        // 262144
    float* xz     = xres   + 262144;           // 1048576
    float* xcT    = xz     + 1048576;          // 524288
    float* dbcT   = xcT    + 524288;           // 540672
    float* deltaT = dbcT   + 540672;           // 524288
    float* sT     = deltaT + 524288;           // 524288
    float* yT     = sT     + 524288;           // 524288
    float* hchain = yT     + 524288;           // B*E*GG*128 = 1048576
    float* dsum   = hchain + 1048576;          // B*E*GG = 8192  (total ~20 MB)

    hipMemcpyAsync(xres, x, (size_t)262144 * sizeof(float),
                   hipMemcpyDeviceToDevice, stream);

    for (int l = 0; l < LL; l++) {
        k_norm_inproj<<<BT/16, 512, 0, stream>>>(
            xres, in_w + (size_t)l*HH*2*EE, in_b + (size_t)l*2*EE,
            norm_w + (size_t)l*HH, xz);
        k_conv<<<128, 256, 0, stream>>>(
            xz, conv_w + (size_t)l*EE*KK, conv_b + (size_t)l*EE, xcT);
        k_plproj<<<BT/8, 320, 0, stream>>>(
            xcT, pl_w + (size_t)l*EE*NJ, pl_b + (size_t)l*NJ, dbcT);
        k_delta<<<EE*8, 256, 0, stream>>>(
            dbcT, dt_w + (size_t)l*RR*EE, dt_b + (size_t)l*EE, xcT, deltaT, sT);
        k_scan_local<<<BB*GG*(EE/4), 128, 0, stream>>>(
            dbcT, deltaT, sT, A_log + (size_t)l*EE*HH, yT, hchain, dsum);
        k_scan_combine<<<BB*EE, 128, 0, stream>>>(
            A_log + (size_t)l*EE*HH, dsum, hchain);
        k_scan_fix<<<BB*(GG-1)*(EE/4), 128, 0, stream>>>(
            dbcT, deltaT, A_log + (size_t)l*EE*HH, hchain, yT);
        k_gate_outproj<<<BT/16, 256, 0, stream>>>(
            yT, xcT, xz, Dp + (size_t)l*EE,
            out_w + (size_t)l*EE*HH, out_b + (size_t)l*HH, xres);
    }
    k_finalnorm<<<BT, 64, 0, stream>>>(xres, fnw, (float*)d_out);
}

// Round 4
// 248.746 us; speedup vs baseline: 1.3784x; 1.1401x over previous
//
#include <hip/hip_runtime.h>
#include <hip/hip_bf16.h>

#define HH 128
#define EE 256
#define KK 4
#define RR 8
#define LL 2
#define BB 2
#define SS 1024
#define BT (BB*SS)      // 2048 tokens total
#define NJ (RR+2*HH)    // 264 dbc rows
#define GG 16           // scan chunks per sequence
#define CH (SS/GG)      // 64 timesteps per chunk
#define EPS 1e-5f
#define LOG2E 1.44269504088896f

__device__ __forceinline__ float silu_f(float v) {
    return v / (1.0f + __expf(-v));
}

// ---------------- K1: rmsnorm + in_proj (+bias) -> xz [2048][512] ------------
__global__ __launch_bounds__(512) void k_norm_inproj(
    const float* __restrict__ xres, const float* __restrict__ inw,
    const float* __restrict__ inb, const float* __restrict__ nw,
    float* __restrict__ xz)
{
    __shared__ float xn[16][128];
    const int bt0 = blockIdx.x * 16;
    const int tid = threadIdx.x;
    {   // phase A: rmsnorm for 16 tokens, 32 threads per token
        const int t = tid >> 5, g = tid & 31;
        const float4 xv = *(const float4*)(xres + (bt0 + t) * HH + g * 4);
        float ss = xv.x*xv.x + xv.y*xv.y + xv.z*xv.z + xv.w*xv.w;
        #pragma unroll
        for (int m = 16; m >= 1; m >>= 1) ss += __shfl_xor(ss, m);
        const float rs = rsqrtf(ss * (1.0f / HH) + EPS);
        const float4 wv = *(const float4*)(nw + g * 4);
        float4 o;
        o.x = xv.x * rs * wv.x; o.y = xv.y * rs * wv.y;
        o.z = xv.z * rs * wv.z; o.w = xv.w * rs * wv.w;
        *(float4*)(&xn[t][g * 4]) = o;
    }
    __syncthreads();
    // phase B: thread = output column j (512), 16-token accumulators
    const int j = tid;
    float acc[16];
    const float bj = inb[j];
    #pragma unroll
    for (int t = 0; t < 16; t++) acc[t] = bj;
    float w0n = inw[0*512 + j], w1n = inw[1*512 + j];
    float w2n = inw[2*512 + j], w3n = inw[3*512 + j];
    for (int k4 = 0; k4 < 32; k4++) {
        const float w0 = w0n, w1 = w1n, w2 = w2n, w3 = w3n;
        if (k4 < 31) {
            const int k = (k4 + 1) * 4;
            w0n = inw[(k+0)*512 + j]; w1n = inw[(k+1)*512 + j];
            w2n = inw[(k+2)*512 + j]; w3n = inw[(k+3)*512 + j];
        }
        const int k = k4 * 4;
        #pragma unroll
        for (int t = 0; t < 16; t++) {
            const float4 xv = *(const float4*)(&xn[t][k]);
            acc[t] += w0*xv.x + w1*xv.y + w2*xv.z + w3*xv.w;
        }
    }
    #pragma unroll
    for (int t = 0; t < 16; t++) xz[(bt0 + t) * 512 + j] = acc[t];
}

// ---------------- K2A: causal conv + silu -> xcT [256][2048] -----------------
__global__ __launch_bounds__(256) void k_conv(
    const float* __restrict__ xz, const float* __restrict__ cw,
    const float* __restrict__ cb, float* __restrict__ xcT)
{
    const int e = threadIdx.x;
    const int tile = blockIdx.x;          // 128 tiles of 16 tokens
    const int b = tile >> 6;
    const int t0 = (tile & 63) * 16;
    const float w0 = cw[e*4+0], w1 = cw[e*4+1], w2 = cw[e*4+2], w3 = cw[e*4+3];
    const float bias = cb[e];
    const float* xp = xz + (size_t)(b * SS) * 512 + e;  // index token via *512
    float xm3 = (t0 >= 3) ? xp[(t0-3)*512] : 0.0f;
    float xm2 = (t0 >= 2) ? xp[(t0-2)*512] : 0.0f;
    float xm1 = (t0 >= 1) ? xp[(t0-1)*512] : 0.0f;
    float* orow = xcT + (size_t)e * BT + b * SS + t0;
    for (int jq = 0; jq < 4; jq++) {
        const int t = t0 + jq * 4;
        float4 ob; float v;
        const float x0 = xp[(t+0)*512];
        v = bias + w3*x0 + w2*xm1 + w1*xm2 + w0*xm3; ob.x = silu_f(v);
        const float x1 = xp[(t+1)*512];
        v = bias + w3*x1 + w2*x0 + w1*xm1 + w0*xm2;  ob.y = silu_f(v);
        const float x2 = xp[(t+2)*512];
        v = bias + w3*x2 + w2*x1 + w1*x0 + w0*xm1;   ob.z = silu_f(v);
        const float x3 = xp[(t+3)*512];
        v = bias + w3*x3 + w2*x2 + w1*x1 + w0*x0;    ob.w = silu_f(v);
        *(float4*)(orow + jq * 4) = ob;
        xm3 = x1; xm2 = x2; xm1 = x3;
    }
}

// ---------------- K2B: pl_proj -> dtrows [8][2048] + BC4 [512][128][8] -------
// BC4[tq][n][0..3] = B for tokens 4tq..4tq+3; [4..7] = C.
__global__ __launch_bounds__(320) void k_plproj(
    const float* __restrict__ xcT, const float* __restrict__ plw,
    const float* __restrict__ plb, float* __restrict__ dtrows,
    float* __restrict__ BC4)
{
    __shared__ float xs[8][256];
    const int bt0 = blockIdx.x * 8;
    const int tid = threadIdx.x;
    if (tid < 256) {
        const int e = tid;
        const float* p = xcT + (size_t)e * BT + bt0;
        const float4 a = *(const float4*)(p);
        const float4 c = *(const float4*)(p + 4);
        xs[0][e] = a.x; xs[1][e] = a.y; xs[2][e] = a.z; xs[3][e] = a.w;
        xs[4][e] = c.x; xs[5][e] = c.y; xs[6][e] = c.z; xs[7][e] = c.w;
    }
    __syncthreads();
    if (tid >= NJ) return;
    const int j = tid;
    float acc[8];
    const float bj = plb[j];
    #pragma unroll
    for (int t = 0; t < 8; t++) acc[t] = bj;
    float w0n = plw[0*NJ + j], w1n = plw[1*NJ + j];
    float w2n = plw[2*NJ + j], w3n = plw[3*NJ + j];
    for (int e4 = 0; e4 < 64; e4++) {
        const float w0 = w0n, w1 = w1n, w2 = w2n, w3 = w3n;
        if (e4 < 63) {
            const int e = (e4 + 1) * 4;
            w0n = plw[(e+0)*NJ + j]; w1n = plw[(e+1)*NJ + j];
            w2n = plw[(e+2)*NJ + j]; w3n = plw[(e+3)*NJ + j];
        }
        const int e = e4 * 4;
        #pragma unroll
        for (int t = 0; t < 8; t++) {
            const float4 xv = *(const float4*)(&xs[t][e]);
            acc[t] += w0*xv.x + w1*xv.y + w2*xv.z + w3*xv.w;
        }
    }
    if (j < RR) {
        float* orow = dtrows + (size_t)j * BT + bt0;
        *(float4*)(orow)     = make_float4(acc[0], acc[1], acc[2], acc[3]);
        *(float4*)(orow + 4) = make_float4(acc[4], acc[5], acc[6], acc[7]);
    } else {
        const int isC = (j >= RR + HH);
        const int nn = isC ? (j - RR - HH) : (j - RR);
        const int tq0 = bt0 >> 2;
        float* p0 = BC4 + ((size_t)tq0 * 128 + nn) * 8 + (isC ? 4 : 0);
        *(float4*)p0 = make_float4(acc[0], acc[1], acc[2], acc[3]);
        float* p1 = BC4 + ((size_t)(tq0 + 1) * 128 + nn) * 8 + (isC ? 4 : 0);
        *(float4*)p1 = make_float4(acc[4], acc[5], acc[6], acc[7]);
    }
}

// -------- K2C: delta = softplus(dt_proj), s = delta*xc, dsum (wave-reduce) ---
__global__ __launch_bounds__(256) void k_delta(
    const float* __restrict__ dtrows, const float* __restrict__ dtw,
    const float* __restrict__ dtb, const float* __restrict__ xcT,
    float* __restrict__ deltaT, float* __restrict__ sT,
    float* __restrict__ dsum)
{
    const int e = blockIdx.x >> 3;
    const int bt = (blockIdx.x & 7) * 256 + threadIdx.x;
    float d = dtb[e];
    #pragma unroll
    for (int r = 0; r < RR; r++) d += dtw[r*EE + e] * dtrows[(size_t)r * BT + bt];
    float sp;
    if (d > 15.0f) sp = d;
    else sp = log1pf(__expf(d));
    const float xc = xcT[(size_t)e * BT + bt];
    deltaT[(size_t)e * BT + bt] = sp;
    sT[(size_t)e * BT + bt] = sp * xc;
    // chunk sum of delta: each 64-lane wave covers one chunk exactly
    float cs = sp;
    #pragma unroll
    for (int m = 1; m <= 32; m <<= 1) cs += __shfl_xor(cs, m);
    if ((threadIdx.x & 63) == 0) {
        const int b = bt >> 10;
        const int g = (bt & 1023) >> 6;
        dsum[(b * EE + e) * GG + g] = cs;
    }
}

// ---------------- K3a: chunk-local scan, 2 e's per block ---------------------
// grid = B*GG*(EE/2) = 4096, block = 128 (n). XCD-swizzled so the 128 blocks
// of one (b,g) land on the same XCD (BC4 stream then hits local L2).
__global__ __launch_bounds__(128, 4) void k_scan_local(
    const float* __restrict__ BC4, const float* __restrict__ deltaT,
    const float* __restrict__ sT, const float* __restrict__ Alog,
    float* __restrict__ yT, float* __restrict__ hchain)
{
    __shared__ float part[2][16][68];
    __shared__ float ybuf[2][CH];
    const int blk = blockIdx.x;
    const int wgid = (blk & 7) * 512 + (blk >> 3);   // bijective
    const int eq = wgid & 127;
    const int r0 = wgid >> 7;       // 0..31 = (b,g)
    const int b = r0 >> 4;
    const int g = r0 & 15;
    const int e0 = eq * 2;
    const int n = threadIdx.x;
    const int t0 = g * CH;

    float An0 = -__expf(Alog[(e0+0) * HH + n]) * LOG2E;
    float An1 = -__expf(Alog[(e0+1) * HH + n]) * LOG2E;
    float h0 = 0.0f, h1 = 0.0f;
    const float* bc = BC4 + ((size_t)((b * 256 + g * 16) * 128 + n)) * 8;
    const float* dr0 = deltaT + (size_t)(e0+0) * BT + b * SS + t0;
    const float* dr1 = deltaT + (size_t)(e0+1) * BT + b * SS + t0;
    const float* sr0 = sT + (size_t)(e0+0) * BT + b * SS + t0;
    const float* sr1 = sT + (size_t)(e0+1) * BT + b * SS + t0;

    float4 pB = *(const float4*)(bc);
    float4 pC = *(const float4*)(bc + 4);
    float4 pd0 = *(const float4*)dr0, pd1 = *(const float4*)dr1;
    float4 ps0 = *(const float4*)sr0, ps1 = *(const float4*)sr1;

    const int tl = n >> 3, jj = n & 7;
    for (int sc = 0; sc < 4; sc++) {
        #pragma unroll
        for (int q = 0; q < 4; q++) {
            const int qq = sc * 4 + q;
            const float4 cB = pB, cC = pC;
            const float4 cd0 = pd0, cd1 = pd1, cs0 = ps0, cs1 = ps1;
            if (qq < 15) {
                const size_t off = (size_t)(qq + 1) * 1024;
                pB = *(const float4*)(bc + off);
                pC = *(const float4*)(bc + off + 4);
                const int t = (qq + 1) * 4;
                pd0 = *(const float4*)(dr0 + t); pd1 = *(const float4*)(dr1 + t);
                ps0 = *(const float4*)(sr0 + t); ps1 = *(const float4*)(sr1 + t);
            }
            float a;
            a = exp2f(cd0.x*An0); h0 = a*h0 + cs0.x*cB.x; part[0][q*4+0][n] = h0*cC.x;
            a = exp2f(cd0.y*An0); h0 = a*h0 + cs0.y*cB.y; part[0][q*4+1][n] = h0*cC.y;
            a = exp2f(cd0.z*An0); h0 = a*h0 + cs0.z*cB.z; part[0][q*4+2][n] = h0*cC.z;
            a = exp2f(cd0.w*An0); h0 = a*h0 + cs0.w*cB.w; part[0][q*4+3][n] = h0*cC.w;
            a = exp2f(cd1.x*An1); h1 = a*h1 + cs1.x*cB.x; part[1][q*4+0][n] = h1*cC.x;
            a = exp2f(cd1.y*An1); h1 = a*h1 + cs1.y*cB.y; part[1][q*4+1][n] = h1*cC.y;
            a = exp2f(cd1.z*An1); h1 = a*h1 + cs1.z*cB.z; part[1][q*4+2][n] = h1*cC.z;
            a = exp2f(cd1.w*An1); h1 = a*h1 + cs1.w*cB.w; part[1][q*4+3][n] = h1*cC.w;
        }
        __syncthreads();
        #pragma unroll
        for (int ee = 0; ee < 2; ee++) {
            float s0 = 0, s1 = 0, s2 = 0, s3 = 0;
            #pragma unroll
            for (int i = 0; i < 4; i++) {
                const float4 p = *(const float4*)(&part[ee][tl][jj*16 + i*4]);
                s0 += p.x; s1 += p.y; s2 += p.z; s3 += p.w;
            }
            float r = (s0 + s1) + (s2 + s3);
            r += __shfl_xor(r, 1); r += __shfl_xor(r, 2); r += __shfl_xor(r, 4);
            if (jj == 0) ybuf[ee][sc*16 + tl] = r;
        }
        __syncthreads();
    }
    {
        const int ee = n >> 6, tt = n & 63;
        yT[(size_t)(e0 + ee) * BT + b * SS + t0 + tt] = ybuf[ee][tt];
    }
    hchain[(size_t)(((b * EE + e0 + 0) * GG) + g) * 128 + n] = h0;
    hchain[(size_t)(((b * EE + e0 + 1) * GG) + g) * 128 + n] = h1;
}

// ---------------- K3b: chain chunk start-states (in-place over hchain) -------
__global__ __launch_bounds__(128) void k_scan_combine(
    const float* __restrict__ Alog, const float* __restrict__ dsum,
    float* __restrict__ hchain)
{
    const int be = blockIdx.x;
    const int e = be & 255;
    const int n = threadIdx.x;
    const float An = -__expf(Alog[e * HH + n]) * LOG2E;
    float h = 0.0f;
    for (int g = 0; g < GG; g++) {
        float* p = hchain + (size_t)(be * GG + g) * 128 + n;
        const float he = *p;
        *p = h;                       // publish h_start for chunk g
        const float ds = dsum[be * GG + g];
        h = exp2f(An * ds) * h + he;
    }
}

// ---------------- K3c: cross-chunk correction, 2 e's per block ---------------
// grid = B*15*(EE/2) = 3840, block = 128 (n)
__global__ __launch_bounds__(128, 4) void k_scan_fix(
    const float* __restrict__ BC4, const float* __restrict__ deltaT,
    const float* __restrict__ Alog, const float* __restrict__ hchain,
    float* __restrict__ yT)
{
    __shared__ float part[2][16][68];
    __shared__ float ybuf[2][CH];
    const int blk = blockIdx.x;
    const int wgid = (blk & 7) * 480 + (blk >> 3);   // bijective
    const int eq = wgid & 127;
    const int r0 = wgid >> 7;       // 0..29
    const int b = r0 / 15;
    const int g = 1 + (r0 % 15);
    const int e0 = eq * 2;
    const int n = threadIdx.x;
    const int t0 = g * CH;

    const float An0 = -__expf(Alog[(e0+0) * HH + n]) * LOG2E;
    const float An1 = -__expf(Alog[(e0+1) * HH + n]) * LOG2E;
    const float w0 = hchain[(size_t)(((b * EE + e0 + 0) * GG) + g) * 128 + n];
    const float w1 = hchain[(size_t)(((b * EE + e0 + 1) * GG) + g) * 128 + n];
    float D0 = 0.0f, D1 = 0.0f;
    const float* bc = BC4 + ((size_t)((b * 256 + g * 16) * 128 + n)) * 8;
    const float* dr0 = deltaT + (size_t)(e0+0) * BT + b * SS + t0;
    const float* dr1 = deltaT + (size_t)(e0+1) * BT + b * SS + t0;

    float4 pC = *(const float4*)(bc + 4);
    float4 pd0 = *(const float4*)dr0, pd1 = *(const float4*)dr1;

    const int tl = n >> 3, jj = n & 7;
    for (int sc = 0; sc < 4; sc++) {
        #pragma unroll
        for (int q = 0; q < 4; q++) {
            const int qq = sc * 4 + q;
            const float4 cC = pC;
            const float4 cd0 = pd0, cd1 = pd1;
            if (qq < 15) {
                const size_t off = (size_t)(qq + 1) * 1024;
                pC = *(const float4*)(bc + off + 4);
                const int t = (qq + 1) * 4;
                pd0 = *(const float4*)(dr0 + t); pd1 = *(const float4*)(dr1 + t);
            }
            D0 += cd0.x; part[0][q*4+0][n] = exp2f(An0*D0) * w0 * cC.x;
            D0 += cd0.y; part[0][q*4+1][n] = exp2f(An0*D0) * w0 * cC.y;
            D0 += cd0.z; part[0][q*4+2][n] = exp2f(An0*D0) * w0 * cC.z;
            D0 += cd0.w; part[0][q*4+3][n] = exp2f(An0*D0) * w0 * cC.w;
            D1 += cd1.x; part[1][q*4+0][n] = exp2f(An1*D1) * w1 * cC.x;
            D1 += cd1.y; part[1][q*4+1][n] = exp2f(An1*D1) * w1 * cC.y;
            D1 += cd1.z; part[1][q*4+2][n] = exp2f(An1*D1) * w1 * cC.z;
            D1 += cd1.w; part[1][q*4+3][n] = exp2f(An1*D1) * w1 * cC.w;
        }
        __syncthreads();
        #pragma unroll
        for (int ee = 0; ee < 2; ee++) {
            float s0 = 0, s1 = 0, s2 = 0, s3 = 0;
            #pragma unroll
            for (int i = 0; i < 4; i++) {
                const float4 p = *(const float4*)(&part[ee][tl][jj*16 + i*4]);
                s0 += p.x; s1 += p.y; s2 += p.z; s3 += p.w;
            }
            float r = (s0 + s1) + (s2 + s3);
            r += __shfl_xor(r, 1); r += __shfl_xor(r, 2); r += __shfl_xor(r, 4);
            if (jj == 0) ybuf[ee][sc*16 + tl] = r;
        }
        __syncthreads();
    }
    {
        const int ee = n >> 6, tt = n & 63;
        yT[(size_t)(e0 + ee) * BT + b * SS + t0 + tt] += ybuf[ee][tt];
    }
}

// ---------------- K4: gate + out_proj + residual (in-place xres) -------------
__global__ __launch_bounds__(256) void k_gate_outproj(
    const float* __restrict__ yT, const float* __restrict__ xcT,
    const float* __restrict__ xz, const float* __restrict__ Dp,
    const float* __restrict__ ow, const float* __restrict__ ob,
    float* __restrict__ xres)
{
    __shared__ float gs[16][256];
    __shared__ float part2[16][128];
    const int bt0 = blockIdx.x * 16;
    const int tid = threadIdx.x;
    {   // phase A: g = (y + Dp*xc) * silu(skip)
        const int e = tid;
        const float dp = Dp[e];
        const float* yp = yT + (size_t)e * BT + bt0;
        const float* xp = xcT + (size_t)e * BT + bt0;
        #pragma unroll
        for (int tq = 0; tq < 4; tq++) {
            const float4 y4 = *(const float4*)(yp + tq * 4);
            const float4 x4 = *(const float4*)(xp + tq * 4);
            float sk;
            sk = xz[(size_t)(bt0 + tq*4 + 0) * 512 + 256 + e];
            gs[tq*4+0][e] = (y4.x + dp * x4.x) * silu_f(sk);
            sk = xz[(size_t)(bt0 + tq*4 + 1) * 512 + 256 + e];
            gs[tq*4+1][e] = (y4.y + dp * x4.y) * silu_f(sk);
            sk = xz[(size_t)(bt0 + tq*4 + 2) * 512 + 256 + e];
            gs[tq*4+2][e] = (y4.z + dp * x4.z) * silu_f(sk);
            sk = xz[(size_t)(bt0 + tq*4 + 3) * 512 + 256 + e];
            gs[tq*4+3][e] = (y4.w + dp * x4.w) * silu_f(sk);
        }
    }
    __syncthreads();
    // phase B: split-K GEMM, thread = (j, kh)
    const int j = tid & 127;
    const int kh = tid >> 7;
    float acc[16];
    #pragma unroll
    for (int t = 0; t < 16; t++) acc[t] = 0.0f;
    const int eb = kh * 128;
    float w0n = ow[(eb+0)*HH + j], w1n = ow[(eb+1)*HH + j];
    float w2n = ow[(eb+2)*HH + j], w3n = ow[(eb+3)*HH + j];
    for (int e4 = 0; e4 < 32; e4++) {
        const float w0 = w0n, w1 = w1n, w2 = w2n, w3 = w3n;
        if (e4 < 31) {
            const int e = eb + (e4 + 1) * 4;
            w0n = ow[(e+0)*HH + j]; w1n = ow[(e+1)*HH + j];
            w2n = ow[(e+2)*HH + j]; w3n = ow[(e+3)*HH + j];
        }
        const int e = eb + e4 * 4;
        #pragma unroll
        for (int t = 0; t < 16; t++) {
            const float4 g4 = *(const float4*)(&gs[t][e]);
            acc[t] += w0*g4.x + w1*g4.y + w2*g4.z + w3*g4.w;
        }
    }
    if (kh == 1) {
        #pragma unroll
        for (int t = 0; t < 16; t++) part2[t][j] = acc[t];
    }
    __syncthreads();
    if (kh == 0) {
        const float bj = ob[j];
        #pragma unroll
        for (int t = 0; t < 16; t++) {
            const float r = acc[t] + part2[t][j] + bj
                          + xres[(size_t)(bt0 + t) * HH + j];
            xres[(size_t)(bt0 + t) * HH + j] = r;
        }
    }
}

// ---------------- K5: final rmsnorm -> d_out ---------------------------------
__global__ __launch_bounds__(64) void k_finalnorm(
    const float* __restrict__ xres, const float* __restrict__ fw,
    float* __restrict__ out)
{
    const int bt = blockIdx.x;
    const int tid = threadIdx.x;
    const float2 v = *(const float2*)(xres + (size_t)bt * HH + tid * 2);
    float ss = v.x*v.x + v.y*v.y;
    #pragma unroll
    for (int m = 32; m >= 1; m >>= 1) ss += __shfl_xor(ss, m);
    const float rs = rsqrtf(ss * (1.0f / HH) + EPS);
    const float2 w = *(const float2*)(fw + tid * 2);
    float2 o; o.x = v.x * rs * w.x; o.y = v.y * rs * w.y;
    *(float2*)(out + (size_t)bt * HH + tid * 2) = o;
}

extern "C" void kernel_launch(void* const* d_in, const int* in_sizes, int n_in,
                              void* d_out, int out_size, void* d_ws, size_t ws_size,
                              hipStream_t stream)
{
    const float* x      = (const float*)d_in[0];
    const float* in_w   = (const float*)d_in[1];
    const float* in_b   = (const float*)d_in[2];
    const float* out_w  = (const float*)d_in[3];
    const float* out_b  = (const float*)d_in[4];
    const float* pl_w   = (const float*)d_in[5];
    const float* pl_b   = (const float*)d_in[6];
    const float* dt_w   = (const float*)d_in[7];
    const float* dt_b   = (const float*)d_in[8];
    const float* conv_w = (const float*)d_in[9];
    const float* conv_b = (const float*)d_in[10];
    const float* A_log  = (const float*)d_in[11];
    const float* Dp     = (const float*)d_in[12];
    const float* norm_w = (const float*)d_in[13];
    const float* fnw    = (const float*)d_in[14];

    float* ws     = (float*)d_ws;
    float* xres   = ws;                        // 262144
    float* xz     = xres   + 262144;           // 1048576
    float* xcT    = xz     + 1048576;          // 524288
    float* dtrows = xcT    + 524288;           // 16384
    float* BC4    = dtrows + 16384;            // 524288
    float* deltaT = BC4    + 524288;           // 524288
    float* sT     = deltaT + 524288;           // 524288
    float* yT     = sT     + 524288;           // 524288
    float* hchain = yT     + 524288;           // 1048576
    float* dsum   = hchain + 1048576;          // 8192   (total ~18 MB)

    hipMemcpyAsync(xres, x, (size_t)262144 * sizeof(float),
                   hipMemcpyDeviceToDevice, stream);

    for (int l = 0; l < LL; l++) {
        k_norm_inproj<<<BT/16, 512, 0, stream>>>(
            xres, in_w + (size_t)l*HH*2*EE, in_b + (size_t)l*2*EE,
            norm_w + (size_t)l*HH, xz);
        k_conv<<<128, 256, 0, stream>>>(
            xz, conv_w + (size_t)l*EE*KK, conv_b + (size_t)l*EE, xcT);
        k_plproj<<<BT/8, 320, 0, stream>>>(
            xcT, pl_w + (size_t)l*EE*NJ, pl_b + (size_t)l*NJ, dtrows, BC4);
        k_delta<<<EE*8, 256, 0, stream>>>(
            dtrows, dt_w + (size_t)l*RR*EE, dt_b + (size_t)l*EE, xcT,
            deltaT, sT, dsum);
        k_scan_local<<<BB*GG*(EE/2), 128, 0, stream>>>(
            BC4, deltaT, sT, A_log + (size_t)l*EE*HH, yT, hchain);
        k_scan_combine<<<BB*EE, 128, 0, stream>>>(
            A_log + (size_t)l*EE*HH, dsum, hchain);
        k_scan_fix<<<BB*(GG-1)*(EE/2), 128, 0, stream>>>(
            BC4, deltaT, A_log + (size_t)l*EE*HH, hchain, yT);
        k_gate_outproj<<<BT/16, 256, 0, stream>>>(
            yT, xcT, xz, Dp + (size_t)l*EE,
            out_w + (size_t)l*EE*HH, out_b + (size_t)l*HH, xres);
    }
    k_finalnorm<<<BT, 64, 0, stream>>>(xres, fnw, (float*)d_out);
}